// Round 4
// baseline (483.737 us; speedup 1.0000x reference)
//
#include <hip/hip_runtime.h>
#include <math.h>

// Problem constants
#define B_    8
#define L_    512
#define K_    16
#define E_    32
#define NH_   64
#define WOFF_ 1

// Workspace layout (floats):
//   qmat  [B][L][32]   @ 0        (131072)
//   kmatT [B][32][L]   @ 131072   (131072)
//   att   [B][L][64]   @ 262144   (262144)
//   gi    [B][L][192]  @ 524288   (786432)

typedef float v2f __attribute__((ext_vector_type(2)));

// ---------------------------------------------------------------------------
// Kernel 1: key_emb -> q, k projections. One thread per (b,l).
// ---------------------------------------------------------------------------
__global__ __launch_bounds__(256) void k_embed(
    const float* __restrict__ ts, const float* __restrict__ Wl,
    const float* __restrict__ bl, const float* __restrict__ Wp,
    const float* __restrict__ bp, const float* __restrict__ Wq,
    const float* __restrict__ bq, const float* __restrict__ Wk,
    const float* __restrict__ bk,
    float* __restrict__ qmat, float* __restrict__ kmatT)
{
    __shared__ float WqL[1024], WkL[1024];
    __shared__ float bqL[32], bkL[32], WpL[31], bpL[31];
    __shared__ float wl0, bl0;
    const int tid = threadIdx.x;

    {
        float4 v = ((const float4*)Wq)[tid];
        ((float4*)WqL)[tid] = v;
        float4 u = ((const float4*)Wk)[tid];
        ((float4*)WkL)[tid] = u;
    }
    if (tid < 32) { bqL[tid] = bq[tid]; bkL[tid] = bk[tid]; }
    if (tid < 31) { WpL[tid] = Wp[tid]; bpL[tid] = bp[tid]; }
    if (tid == 0) { wl0 = Wl[0]; bl0 = bl[0]; }
    __syncthreads();

    const int p = blockIdx.x * 256 + tid;      // 0..4095
    const float t = ts[p];
    float e[32];
    e[0] = t * wl0 + bl0;
    #pragma unroll
    for (int j = 1; j < 32; ++j) e[j] = sinf(t * WpL[j - 1] + bpL[j - 1]);

    const int b = p >> 9, l = p & 511;
    float4* qm4 = (float4*)(qmat + (size_t)p * 32);
    float*  kT  = kmatT + (size_t)b * 32 * 512 + l;

    for (int dq = 0; dq < 8; ++dq) {
        float q0 = bqL[4*dq+0], q1 = bqL[4*dq+1], q2 = bqL[4*dq+2], q3 = bqL[4*dq+3];
        float k0 = bkL[4*dq+0], k1 = bkL[4*dq+1], k2 = bkL[4*dq+2], k3 = bkL[4*dq+3];
        const float* wq = &WqL[(4*dq) * 32];
        const float* wk = &WkL[(4*dq) * 32];
        #pragma unroll
        for (int j = 0; j < 32; ++j) {
            const float ej = e[j];
            q0 = fmaf(wq[j],      ej, q0);
            q1 = fmaf(wq[32 + j], ej, q1);
            q2 = fmaf(wq[64 + j], ej, q2);
            q3 = fmaf(wq[96 + j], ej, q3);
            k0 = fmaf(wk[j],      ej, k0);
            k1 = fmaf(wk[32 + j], ej, k1);
            k2 = fmaf(wk[64 + j], ej, k2);
            k3 = fmaf(wk[96 + j], ej, k3);
        }
        qm4[dq] = make_float4(q0, q1, q2, q3);
        kT[(4*dq + 0) * 512] = k0;
        kT[(4*dq + 1) * 512] = k1;
        kT[(4*dq + 2) * 512] = k2;
        kT[(4*dq + 3) * 512] = k3;
    }
}

// ---------------------------------------------------------------------------
// Kernel 2: per-(b,q) attention -> att_out.  grid (32 qb, 8 b), 256 thr.
// ---------------------------------------------------------------------------
__global__ __launch_bounds__(256) void k_attn(
    const float* __restrict__ qmat, const float* __restrict__ kmatT,
    const float* __restrict__ val,  const int*   __restrict__ mark,
    const float* __restrict__ npm,  const float* __restrict__ Wo,
    const float* __restrict__ bo,   float* __restrict__ att)
{
    __shared__ float srow[4 * 512];   // per-wave score row
    __shared__ int   cc[512];         // category (-1 if padded)
    __shared__ float vv[512];         // values
    const int tid = threadIdx.x;
    const int qb  = blockIdx.x;       // 0..31
    const int b   = blockIdx.y;       // 0..7

    for (int k = tid; k < 512; k += 256) {
        const int   m  = mark[b * 512 + k];
        const float np = npm[b * 512 + k];
        cc[k] = (np > 0.0f) ? (m - 1) : -1;
        vv[k] = val[b * 512 + k];
    }
    __syncthreads();

    const int w = tid >> 6, lane = tid & 63;
    const float* kTb = kmatT + (size_t)b * 32 * 512;

    for (int iq = 0; iq < 4; ++iq) {
        const int q = qb * 16 + w * 4 + iq;

        float qr[32];
        const float4* qm4 = (const float4*)(qmat + (size_t)(b * 512 + q) * 32);
        #pragma unroll
        for (int j4 = 0; j4 < 8; ++j4) {
            float4 v = qm4[j4];
            qr[4*j4+0] = v.x; qr[4*j4+1] = v.y; qr[4*j4+2] = v.z; qr[4*j4+3] = v.w;
        }

        float acc[8];
        #pragma unroll
        for (int m = 0; m < 8; ++m) acc[m] = 0.0f;
        #pragma unroll 4
        for (int j = 0; j < 32; ++j) {
            const float* row = kTb + j * 512 + lane;
            const float  qj  = qr[j];
            #pragma unroll
            for (int m = 0; m < 8; ++m) acc[m] = fmaf(qj, row[m * 64], acc[m]);
        }
        #pragma unroll
        for (int m = 0; m < 8; ++m)
            srow[w * 512 + m * 64 + lane] = acc[m] * 0.17677669529663687f;
        __syncthreads();

        const int c = lane & 15, s = lane >> 4;
        float mx = -1e30f, Z = 0.0f, X = 0.0f;
        const int base = s * 128;
        for (int t = 0; t < 128; ++t) {
            const int k = base + ((t + s) & 127);
            if (cc[k] == c) {
                const float l  = (k <= q + WOFF_) ? srow[w * 512 + k] : 0.0f;
                const float mn = fmaxf(mx, l);
                const float e1 = __expf(l - mn);
                const float sc = __expf(mx - mn);
                Z = Z * sc + e1;
                X = X * sc + e1 * vv[k];
                mx = mn;
            }
        }
        #pragma unroll
        for (int off = 16; off <= 32; off <<= 1) {
            const float mo = __shfl_xor(mx, off);
            const float Zo = __shfl_xor(Z, off);
            const float Xo = __shfl_xor(X, off);
            const float mn = fmaxf(mx, mo);
            const float a0 = __expf(mx - mn);
            const float a1 = __expf(mo - mn);
            Z = Z * a0 + Zo * a1;
            X = X * a0 + Xo * a1;
            mx = mn;
        }
        const float x = (Z > 0.0f) ? X / Z : 0.0f;

        float xs[16];
        #pragma unroll
        for (int c2 = 0; c2 < 16; ++c2) xs[c2] = __shfl(x, c2);

        const float4* wo4 = (const float4*)(Wo + lane * 16);
        float a = bo[lane];
        #pragma unroll
        for (int c4 = 0; c4 < 4; ++c4) {
            float4 v = wo4[c4];
            a += xs[4*c4+0] * v.x + xs[4*c4+1] * v.y + xs[4*c4+2] * v.z + xs[4*c4+3] * v.w;
        }
        att[(size_t)(b * 512 + q) * 64 + lane] = a;
        __syncthreads();
    }
}

// ---------------------------------------------------------------------------
// Kernel 3: gi = att @ W_ih^T + b_ih.  256 blocks x 16 rows each.
// ---------------------------------------------------------------------------
__global__ __launch_bounds__(256) void k_gi(
    const float* __restrict__ att, const float* __restrict__ Wih,
    const float* __restrict__ bih, float* __restrict__ gi)
{
    __shared__ float WL[192 * 65];
    __shared__ float attL[16 * 64];
    __shared__ float bL[192];
    const int tid = threadIdx.x;

    for (int idx = tid; idx < 3072; idx += 256) {
        float4 v = ((const float4*)Wih)[idx];
        const int g = idx >> 4, jq = idx & 15;
        float* dst = &WL[g * 65 + jq * 4];
        dst[0] = v.x; dst[1] = v.y; dst[2] = v.z; dst[3] = v.w;
    }
    if (tid < 192) bL[tid] = bih[tid];
    {
        float4 v = ((const float4*)att)[blockIdx.x * 256 + tid];
        ((float4*)attL)[tid] = v;
    }
    __syncthreads();

    const size_t out0 = (size_t)blockIdx.x * 16 * 192;
    for (int pp = 0; pp < 12; ++pp) {
        const int p = tid + 256 * pp;
        const int r = p / 192, g = p - r * 192;
        float a0 = bL[g], a1 = 0.f, a2 = 0.f, a3 = 0.f;
        const float* wrow = &WL[g * 65];
        const float* arow = &attL[r * 64];
        #pragma unroll
        for (int j = 0; j < 64; j += 4) {
            a0 = fmaf(arow[j + 0], wrow[j + 0], a0);
            a1 = fmaf(arow[j + 1], wrow[j + 1], a1);
            a2 = fmaf(arow[j + 2], wrow[j + 2], a2);
            a3 = fmaf(arow[j + 3], wrow[j + 3], a3);
        }
        gi[out0 + p] = (a0 + a1) + (a2 + a3);
    }
}

// ---------------------------------------------------------------------------
// Kernel 4: sequential GRU — one wave per batch, LDS h-broadcast,
//           NO barrier, 4-deep gi register prefetch.
//
// Round-3 post-mortem: LDS broadcast alone was neutral (212 vs 216 us).
// Corrected VALUBusy (8 waves = 0.78% full-busy): r3 wave is 51% VALU-busy
// => ~490 cy/step of stall. Cause: __syncthreads forces the compiler to
// emit s_waitcnt vmcnt(0) lgkmcnt(0) EVERY step, draining (a) gi prefetch
// loads issued only ~300 cy earlier (HBM latency ~900 cy; FETCH_SIZE shows
// 1.76 MB of the 3 MB gi misses to HBM) and (b) the outb store ack.
//
// Fix: (1) drop __syncthreads — single wave per block, ds_write->ds_read
// same-address ordering is guaranteed by the compiler's lgkmcnt waits
// (intra-wave, in-order DS). No barrier => no vmcnt(0) drain.
// (2) 4-step-deep register ring for gi (12 loads in flight, slot refilled
// right after consumption) => counted vmcnt waits, ~1500+ cy of cover.
// Per-batch arithmetic sequence remains bit-identical to round 0/3.
// ---------------------------------------------------------------------------
__global__ __launch_bounds__(64, 1) void k_gru(
    const float* __restrict__ gi, const float* __restrict__ Whh,
    const float* __restrict__ bhh, float* __restrict__ out)
{
    __shared__ float hs[64];
    const int lane = threadIdx.x;     // 0..63
    const int b    = blockIdx.x;      // 0..7

    // Stage this lane's three W_hh rows into registers (as 32 x v2f each).
    v2f wr[32], wz[32], wn[32];
    {
        const v2f* r2 = (const v2f*)(Whh + (size_t)lane * 64);
        const v2f* z2 = (const v2f*)(Whh + (size_t)(lane + 64) * 64);
        const v2f* n2 = (const v2f*)(Whh + (size_t)(lane + 128) * 64);
        #pragma unroll
        for (int j = 0; j < 32; ++j) {
            wr[j] = r2[j];
            wz[j] = z2[j];
            wn[j] = n2[j];
        }
    }
    const float br = bhh[lane];
    const float bz = bhh[lane + 64];
    const float bn = bhh[lane + 128];

    const float* gib  = gi  + (size_t)b * 512 * 192;
    float*       outb = out + (size_t)b * 512 * 64;

    float h = 0.0f;
    hs[lane] = 0.0f;                  // h_{-1} = 0 (same wave; lgkmcnt orders)

    // 4-deep gi prefetch ring (static indices -> registers)
    float pr[4], pz[4], pn[4];
    #pragma unroll
    for (int i = 0; i < 4; ++i) {
        const float* gp = gib + (size_t)i * 192;
        pr[i] = gp[lane];
        pz[i] = gp[lane + 64];
        pn[i] = gp[lane + 128];
    }

    const float4* hs4 = (const float4*)hs;

    for (int tt = 0; tt < 512; tt += 4) {
        #pragma unroll
        for (int u = 0; u < 4; ++u) {
            const int t = tt + u;

            // broadcast-read h (uniform address -> LDS broadcast)
            float4 hv[16];
            #pragma unroll
            for (int k = 0; k < 16; ++k) hv[k] = hs4[k];

            // consume slot u, then refill it for step t+4 (fire-and-forget)
            const float gr = pr[u], gz = pz[u], gn = pn[u];
            {
                const int tn = (t + 4 < 512) ? (t + 4) : 511;  // clamped, branchless
                const float* gp = gib + (size_t)tn * 192;
                pr[u] = gp[lane];
                pz[u] = gp[lane + 64];
                pn[u] = gp[lane + 128];
            }

            // matvec: pure-VGPR v_pk_fma stream; accumulation order identical
            // to the verified round-0/3 kernels (pairs (2k, 2k+1) in sequence).
            v2f ar2 = {gr + br, 0.0f};
            v2f az2 = {gz + bz, 0.0f};
            v2f an2 = {bn, 0.0f};
            #pragma unroll
            for (int k = 0; k < 16; ++k) {
                v2f p0, p1;
                p0.x = hv[k].x; p0.y = hv[k].y;
                p1.x = hv[k].z; p1.y = hv[k].w;
                ar2 = wr[2*k]     * p0 + ar2;
                az2 = wz[2*k]     * p0 + az2;
                an2 = wn[2*k]     * p0 + an2;
                ar2 = wr[2*k + 1] * p1 + ar2;
                az2 = wz[2*k + 1] * p1 + az2;
                an2 = wn[2*k + 1] * p1 + an2;
            }
            const float ar = ar2.x + ar2.y;
            const float az = az2.x + az2.y;
            const float hn = an2.x + an2.y;

            // activations (identical op sequence to round-0)
            const float r = __builtin_amdgcn_rcpf(1.0f + __expf(-ar));
            const float z = __builtin_amdgcn_rcpf(1.0f + __expf(-az));
            float npre = gn + r * hn;
            npre = fminf(fmaxf(npre, -15.0f), 15.0f);
            const float e2 = __expf(2.0f * npre);
            const float n  = (e2 - 1.0f) * __builtin_amdgcn_rcpf(e2 + 1.0f);

            h = fmaf(z, h - n, n);        // (1-z)*n + z*h

            hs[lane] = h;                 // next step's broadcast source
            outb[t * 64 + lane] = h;      // fire-and-forget store
        }
    }
}

// ---------------------------------------------------------------------------
extern "C" void kernel_launch(void* const* d_in, const int* in_sizes, int n_in,
                              void* d_out, int out_size, void* d_ws, size_t ws_size,
                              hipStream_t stream)
{
    const float* ts   = (const float*)d_in[0];
    const float* val  = (const float*)d_in[1];
    const int*   mark = (const int*)  d_in[2];
    const float* npm  = (const float*)d_in[3];
    const float* Wl   = (const float*)d_in[4];
    const float* bl   = (const float*)d_in[5];
    const float* Wp   = (const float*)d_in[6];
    const float* bp   = (const float*)d_in[7];
    const float* Wq   = (const float*)d_in[8];
    const float* bq   = (const float*)d_in[9];
    const float* Wk   = (const float*)d_in[10];
    const float* bk   = (const float*)d_in[11];
    const float* Wo   = (const float*)d_in[12];
    const float* bo   = (const float*)d_in[13];
    const float* Wih  = (const float*)d_in[14];
    const float* Whh  = (const float*)d_in[15];
    const float* bih  = (const float*)d_in[16];
    const float* bhh  = (const float*)d_in[17];

    float* ws    = (float*)d_ws;
    float* qmat  = ws;                 // 131072
    float* kmatT = ws + 131072;        // 131072
    float* att   = ws + 262144;        // 262144
    float* gi    = ws + 524288;        // 786432
    float* out   = (float*)d_out;

    k_embed<<<16, 256, 0, stream>>>(ts, Wl, bl, Wp, bp, Wq, bq, Wk, bk, qmat, kmatT);
    k_attn<<<dim3(32, 8), 256, 0, stream>>>(qmat, kmatT, val, mark, npm, Wo, bo, att);
    k_gi<<<256, 256, 0, stream>>>(att, Wih, bih, gi);
    k_gru<<<8, 64, 0, stream>>>(gi, Whh, bhh, out);
}

// Round 5
// 448.080 us; speedup vs baseline: 1.0796x; 1.0796x over previous
//
#include <hip/hip_runtime.h>
#include <math.h>

// Problem constants
#define B_    8
#define L_    512
#define K_    16
#define E_    32
#define NH_   64
#define WOFF_ 1

// Workspace layout (floats):
//   qmat  [B][L][32]   @ 0        (131072)
//   kmatT [B][32][L]   @ 131072   (131072)
//   att   [B][L][64]   @ 262144   (262144)
//   gi    [B][L][192]  @ 524288   (786432)

typedef float v2f __attribute__((ext_vector_type(2)));
typedef float v4f __attribute__((ext_vector_type(4)));

// ---------------------------------------------------------------------------
// Kernel 1: key_emb -> q, k projections. One thread per (b,l).
// ---------------------------------------------------------------------------
__global__ __launch_bounds__(256) void k_embed(
    const float* __restrict__ ts, const float* __restrict__ Wl,
    const float* __restrict__ bl, const float* __restrict__ Wp,
    const float* __restrict__ bp, const float* __restrict__ Wq,
    const float* __restrict__ bq, const float* __restrict__ Wk,
    const float* __restrict__ bk,
    float* __restrict__ qmat, float* __restrict__ kmatT)
{
    __shared__ float WqL[1024], WkL[1024];
    __shared__ float bqL[32], bkL[32], WpL[31], bpL[31];
    __shared__ float wl0, bl0;
    const int tid = threadIdx.x;

    {
        float4 v = ((const float4*)Wq)[tid];
        ((float4*)WqL)[tid] = v;
        float4 u = ((const float4*)Wk)[tid];
        ((float4*)WkL)[tid] = u;
    }
    if (tid < 32) { bqL[tid] = bq[tid]; bkL[tid] = bk[tid]; }
    if (tid < 31) { WpL[tid] = Wp[tid]; bpL[tid] = bp[tid]; }
    if (tid == 0) { wl0 = Wl[0]; bl0 = bl[0]; }
    __syncthreads();

    const int p = blockIdx.x * 256 + tid;      // 0..4095
    const float t = ts[p];
    float e[32];
    e[0] = t * wl0 + bl0;
    #pragma unroll
    for (int j = 1; j < 32; ++j) e[j] = sinf(t * WpL[j - 1] + bpL[j - 1]);

    const int b = p >> 9, l = p & 511;
    float4* qm4 = (float4*)(qmat + (size_t)p * 32);
    float*  kT  = kmatT + (size_t)b * 32 * 512 + l;

    for (int dq = 0; dq < 8; ++dq) {
        float q0 = bqL[4*dq+0], q1 = bqL[4*dq+1], q2 = bqL[4*dq+2], q3 = bqL[4*dq+3];
        float k0 = bkL[4*dq+0], k1 = bkL[4*dq+1], k2 = bkL[4*dq+2], k3 = bkL[4*dq+3];
        const float* wq = &WqL[(4*dq) * 32];
        const float* wk = &WkL[(4*dq) * 32];
        #pragma unroll
        for (int j = 0; j < 32; ++j) {
            const float ej = e[j];
            q0 = fmaf(wq[j],      ej, q0);
            q1 = fmaf(wq[32 + j], ej, q1);
            q2 = fmaf(wq[64 + j], ej, q2);
            q3 = fmaf(wq[96 + j], ej, q3);
            k0 = fmaf(wk[j],      ej, k0);
            k1 = fmaf(wk[32 + j], ej, k1);
            k2 = fmaf(wk[64 + j], ej, k2);
            k3 = fmaf(wk[96 + j], ej, k3);
        }
        qm4[dq] = make_float4(q0, q1, q2, q3);
        kT[(4*dq + 0) * 512] = k0;
        kT[(4*dq + 1) * 512] = k1;
        kT[(4*dq + 2) * 512] = k2;
        kT[(4*dq + 3) * 512] = k3;
    }
}

// ---------------------------------------------------------------------------
// Kernel 2: per-(b,q) attention -> att_out.  grid (32 qb, 8 b), 256 thr.
// ---------------------------------------------------------------------------
__global__ __launch_bounds__(256) void k_attn(
    const float* __restrict__ qmat, const float* __restrict__ kmatT,
    const float* __restrict__ val,  const int*   __restrict__ mark,
    const float* __restrict__ npm,  const float* __restrict__ Wo,
    const float* __restrict__ bo,   float* __restrict__ att)
{
    __shared__ float srow[4 * 512];   // per-wave score row
    __shared__ int   cc[512];         // category (-1 if padded)
    __shared__ float vv[512];         // values
    const int tid = threadIdx.x;
    const int qb  = blockIdx.x;       // 0..31
    const int b   = blockIdx.y;       // 0..7

    for (int k = tid; k < 512; k += 256) {
        const int   m  = mark[b * 512 + k];
        const float np = npm[b * 512 + k];
        cc[k] = (np > 0.0f) ? (m - 1) : -1;
        vv[k] = val[b * 512 + k];
    }
    __syncthreads();

    const int w = tid >> 6, lane = tid & 63;
    const float* kTb = kmatT + (size_t)b * 32 * 512;

    for (int iq = 0; iq < 4; ++iq) {
        const int q = qb * 16 + w * 4 + iq;

        float qr[32];
        const float4* qm4 = (const float4*)(qmat + (size_t)(b * 512 + q) * 32);
        #pragma unroll
        for (int j4 = 0; j4 < 8; ++j4) {
            float4 v = qm4[j4];
            qr[4*j4+0] = v.x; qr[4*j4+1] = v.y; qr[4*j4+2] = v.z; qr[4*j4+3] = v.w;
        }

        float acc[8];
        #pragma unroll
        for (int m = 0; m < 8; ++m) acc[m] = 0.0f;
        #pragma unroll 4
        for (int j = 0; j < 32; ++j) {
            const float* row = kTb + j * 512 + lane;
            const float  qj  = qr[j];
            #pragma unroll
            for (int m = 0; m < 8; ++m) acc[m] = fmaf(qj, row[m * 64], acc[m]);
        }
        #pragma unroll
        for (int m = 0; m < 8; ++m)
            srow[w * 512 + m * 64 + lane] = acc[m] * 0.17677669529663687f;
        __syncthreads();

        const int c = lane & 15, s = lane >> 4;
        float mx = -1e30f, Z = 0.0f, X = 0.0f;
        const int base = s * 128;
        for (int t = 0; t < 128; ++t) {
            const int k = base + ((t + s) & 127);
            if (cc[k] == c) {
                const float l  = (k <= q + WOFF_) ? srow[w * 512 + k] : 0.0f;
                const float mn = fmaxf(mx, l);
                const float e1 = __expf(l - mn);
                const float sc = __expf(mx - mn);
                Z = Z * sc + e1;
                X = X * sc + e1 * vv[k];
                mx = mn;
            }
        }
        #pragma unroll
        for (int off = 16; off <= 32; off <<= 1) {
            const float mo = __shfl_xor(mx, off);
            const float Zo = __shfl_xor(Z, off);
            const float Xo = __shfl_xor(X, off);
            const float mn = fmaxf(mx, mo);
            const float a0 = __expf(mx - mn);
            const float a1 = __expf(mo - mn);
            Z = Z * a0 + Zo * a1;
            X = X * a0 + Xo * a1;
            mx = mn;
        }
        const float x = (Z > 0.0f) ? X / Z : 0.0f;

        float xs[16];
        #pragma unroll
        for (int c2 = 0; c2 < 16; ++c2) xs[c2] = __shfl(x, c2);

        const float4* wo4 = (const float4*)(Wo + lane * 16);
        float a = bo[lane];
        #pragma unroll
        for (int c4 = 0; c4 < 4; ++c4) {
            float4 v = wo4[c4];
            a += xs[4*c4+0] * v.x + xs[4*c4+1] * v.y + xs[4*c4+2] * v.z + xs[4*c4+3] * v.w;
        }
        att[(size_t)(b * 512 + q) * 64 + lane] = a;
        __syncthreads();
    }
}

// ---------------------------------------------------------------------------
// Kernel 3: gi = att @ W_ih^T + b_ih.  256 blocks x 16 rows each.
// ---------------------------------------------------------------------------
__global__ __launch_bounds__(256) void k_gi(
    const float* __restrict__ att, const float* __restrict__ Wih,
    const float* __restrict__ bih, float* __restrict__ gi)
{
    __shared__ float WL[192 * 65];
    __shared__ float attL[16 * 64];
    __shared__ float bL[192];
    const int tid = threadIdx.x;

    for (int idx = tid; idx < 3072; idx += 256) {
        float4 v = ((const float4*)Wih)[idx];
        const int g = idx >> 4, jq = idx & 15;
        float* dst = &WL[g * 65 + jq * 4];
        dst[0] = v.x; dst[1] = v.y; dst[2] = v.z; dst[3] = v.w;
    }
    if (tid < 192) bL[tid] = bih[tid];
    {
        float4 v = ((const float4*)att)[blockIdx.x * 256 + tid];
        ((float4*)attL)[tid] = v;
    }
    __syncthreads();

    const size_t out0 = (size_t)blockIdx.x * 16 * 192;
    for (int pp = 0; pp < 12; ++pp) {
        const int p = tid + 256 * pp;
        const int r = p / 192, g = p - r * 192;
        float a0 = bL[g], a1 = 0.f, a2 = 0.f, a3 = 0.f;
        const float* wrow = &WL[g * 65];
        const float* arow = &attL[r * 64];
        #pragma unroll
        for (int j = 0; j < 64; j += 4) {
            a0 = fmaf(arow[j + 0], wrow[j + 0], a0);
            a1 = fmaf(arow[j + 1], wrow[j + 1], a1);
            a2 = fmaf(arow[j + 2], wrow[j + 2], a2);
            a3 = fmaf(arow[j + 3], wrow[j + 3], a3);
        }
        gi[out0 + p] = (a0 + a1) + (a2 + a3);
    }
}

// ---------------------------------------------------------------------------
// Kernel 4: sequential GRU — one wave per batch, LDS h-broadcast, no
// barrier, 4-deep gi ring, LEAN issue stream.
//
// r3/r4 post-mortem (full-busy for 8 waves = 0.781% VALUBusy):
//   r3 (barrier, 1-deep):   993 cy/step = 508 VALU + 485 stall
//   r4 (no barrier, 4-deep): ~1000     = 640 VALU + 355 stall
// r4's structure cut stall by 130 cy/step but its implementation added
// ~85 VALU insts/step: clamped tn select + fresh 64-bit address per ring
// refill, float4->v2f repack movs, per-step out addressing. This round
// keeps r4's stall win and removes the VALU bloat:
//   - ring refill from ONE incremented pointer (pf += 192), no clamp:
//     last 4-step group peeled into an epilogue (no refill there)
//   - broadcast reads via v4f + __builtin_shufflevector sub-register
//     aliasing (exact register-pair refs, no repack movs)
//   - output via incremented pointer
// FP op sequence bit-identical to rounds 0-4.
// ---------------------------------------------------------------------------

#define GRU_STEP(u, DO_REFILL) {                                           \
    /* broadcast-read h (uniform addr -> LDS broadcast) */                 \
    v2f hp[32];                                                            \
    _Pragma("unroll")                                                      \
    for (int k = 0; k < 16; ++k) {                                         \
        v4f t4 = hs4[k];                                                   \
        hp[2*k]   = __builtin_shufflevector(t4, t4, 0, 1);                 \
        hp[2*k+1] = __builtin_shufflevector(t4, t4, 2, 3);                 \
    }                                                                      \
    const float gr = pr[u], gz = pz[u], gn = pn[u];                        \
    if (DO_REFILL) {                                                       \
        pr[u] = pf[0];                                                     \
        pz[u] = pf[64];                                                    \
        pn[u] = pf[128];                                                   \
        pf += 192;                                                         \
    }                                                                      \
    v2f ar2 = {gr + br, 0.0f};                                             \
    v2f az2 = {gz + bz, 0.0f};                                             \
    v2f an2 = {bn, 0.0f};                                                  \
    _Pragma("unroll")                                                      \
    for (int j = 0; j < 32; ++j) {                                         \
        ar2 = wr[j] * hp[j] + ar2;   /* v_pk_fma_f32, 3 chains interleave */\
        az2 = wz[j] * hp[j] + az2;                                         \
        an2 = wn[j] * hp[j] + an2;                                         \
    }                                                                      \
    const float ar = ar2.x + ar2.y;                                        \
    const float az = az2.x + az2.y;                                        \
    const float hn = an2.x + an2.y;                                        \
    const float r = __builtin_amdgcn_rcpf(1.0f + __expf(-ar));             \
    const float z = __builtin_amdgcn_rcpf(1.0f + __expf(-az));             \
    float npre = gn + r * hn;                                              \
    npre = fminf(fmaxf(npre, -15.0f), 15.0f);                              \
    const float e2 = __expf(2.0f * npre);                                  \
    const float n  = (e2 - 1.0f) * __builtin_amdgcn_rcpf(e2 + 1.0f);       \
    h = fmaf(z, h - n, n);            /* (1-z)*n + z*h */                  \
    hs[lane] = h;                     /* next step's broadcast source */   \
    *outp = h;                        /* fire-and-forget */                \
    outp += 64;                                                            \
}

__global__ __launch_bounds__(64, 1) void k_gru(
    const float* __restrict__ gi, const float* __restrict__ Whh,
    const float* __restrict__ bhh, float* __restrict__ out)
{
    __shared__ float hs[64];
    const int lane = threadIdx.x;     // 0..63
    const int b    = blockIdx.x;      // 0..7

    // Stage this lane's three W_hh rows into registers (as 32 x v2f each).
    v2f wr[32], wz[32], wn[32];
    {
        const v2f* r2 = (const v2f*)(Whh + (size_t)lane * 64);
        const v2f* z2 = (const v2f*)(Whh + (size_t)(lane + 64) * 64);
        const v2f* n2 = (const v2f*)(Whh + (size_t)(lane + 128) * 64);
        #pragma unroll
        for (int j = 0; j < 32; ++j) {
            wr[j] = r2[j];
            wz[j] = z2[j];
            wn[j] = n2[j];
        }
    }
    const float br = bhh[lane];
    const float bz = bhh[lane + 64];
    const float bn = bhh[lane + 128];

    const float* gib  = gi  + (size_t)b * 512 * 192;
    float*       outp = out + (size_t)b * 512 * 64 + lane;

    float h = 0.0f;
    hs[lane] = 0.0f;                  // h_{-1} = 0 (same wave; DS in-order)

    // 4-deep gi prefetch ring (unrolled static indices -> registers)
    float pr[4], pz[4], pn[4];
    #pragma unroll
    for (int i = 0; i < 4; ++i) {
        const float* gp = gib + (size_t)i * 192;
        pr[i] = gp[lane];
        pz[i] = gp[lane + 64];
        pn[i] = gp[lane + 128];
    }
    // refill pointer: lane offset baked in, advanced +192 per step
    const float* pf = gib + (size_t)4 * 192 + lane;

    const v4f* hs4 = (const v4f*)hs;

    // main loop: 127 groups, steps 0..507, refills rows 4..511
    for (int tt = 0; tt < 508; tt += 4) {
        #pragma unroll
        for (int u = 0; u < 4; ++u) {
            GRU_STEP(u, 1)
        }
    }
    // epilogue: steps 508..511 from the ring, no refill
    #pragma unroll
    for (int u = 0; u < 4; ++u) {
        GRU_STEP(u, 0)
    }
}

// ---------------------------------------------------------------------------
extern "C" void kernel_launch(void* const* d_in, const int* in_sizes, int n_in,
                              void* d_out, int out_size, void* d_ws, size_t ws_size,
                              hipStream_t stream)
{
    const float* ts   = (const float*)d_in[0];
    const float* val  = (const float*)d_in[1];
    const int*   mark = (const int*)  d_in[2];
    const float* npm  = (const float*)d_in[3];
    const float* Wl   = (const float*)d_in[4];
    const float* bl   = (const float*)d_in[5];
    const float* Wp   = (const float*)d_in[6];
    const float* bp   = (const float*)d_in[7];
    const float* Wq   = (const float*)d_in[8];
    const float* bq   = (const float*)d_in[9];
    const float* Wk   = (const float*)d_in[10];
    const float* bk   = (const float*)d_in[11];
    const float* Wo   = (const float*)d_in[12];
    const float* bo   = (const float*)d_in[13];
    const float* Wih  = (const float*)d_in[14];
    const float* Whh  = (const float*)d_in[15];
    const float* bih  = (const float*)d_in[16];
    const float* bhh  = (const float*)d_in[17];

    float* ws    = (float*)d_ws;
    float* qmat  = ws;                 // 131072
    float* kmatT = ws + 131072;        // 131072
    float* att   = ws + 262144;        // 262144
    float* gi    = ws + 524288;        // 786432
    float* out   = (float*)d_out;

    k_embed<<<16, 256, 0, stream>>>(ts, Wl, bl, Wp, bp, Wq, bq, Wk, bk, qmat, kmatT);
    k_attn<<<dim3(32, 8), 256, 0, stream>>>(qmat, kmatT, val, mark, npm, Wo, bo, att);
    k_gi<<<256, 256, 0, stream>>>(att, Wih, bih, gi);
    k_gru<<<8, 64, 0, stream>>>(gi, Whh, bhh, out);
}

// Round 6
// 434.627 us; speedup vs baseline: 1.1130x; 1.0310x over previous
//
#include <hip/hip_runtime.h>
#include <math.h>

// Problem constants
#define B_    8
#define L_    512
#define K_    16
#define E_    32
#define NH_   64
#define WOFF_ 1

// Workspace layout (floats):
//   qmat  [B][L][32]   @ 0        (131072)
//   kmatT [B][32][L]   @ 131072   (131072)
//   att   [B][L][64]   @ 262144   (262144)
//   gi    [B][L][192]  @ 524288   (786432)

typedef float v2f __attribute__((ext_vector_type(2)));
typedef float v4f __attribute__((ext_vector_type(4)));

// ---------------------------------------------------------------------------
// Kernel 1: key_emb -> q, k projections. One thread per (b,l).
// ---------------------------------------------------------------------------
__global__ __launch_bounds__(256) void k_embed(
    const float* __restrict__ ts, const float* __restrict__ Wl,
    const float* __restrict__ bl, const float* __restrict__ Wp,
    const float* __restrict__ bp, const float* __restrict__ Wq,
    const float* __restrict__ bq, const float* __restrict__ Wk,
    const float* __restrict__ bk,
    float* __restrict__ qmat, float* __restrict__ kmatT)
{
    __shared__ float WqL[1024], WkL[1024];
    __shared__ float bqL[32], bkL[32], WpL[31], bpL[31];
    __shared__ float wl0, bl0;
    const int tid = threadIdx.x;

    {
        float4 v = ((const float4*)Wq)[tid];
        ((float4*)WqL)[tid] = v;
        float4 u = ((const float4*)Wk)[tid];
        ((float4*)WkL)[tid] = u;
    }
    if (tid < 32) { bqL[tid] = bq[tid]; bkL[tid] = bk[tid]; }
    if (tid < 31) { WpL[tid] = Wp[tid]; bpL[tid] = bp[tid]; }
    if (tid == 0) { wl0 = Wl[0]; bl0 = bl[0]; }
    __syncthreads();

    const int p = blockIdx.x * 256 + tid;      // 0..4095
    const float t = ts[p];
    float e[32];
    e[0] = t * wl0 + bl0;
    #pragma unroll
    for (int j = 1; j < 32; ++j) e[j] = sinf(t * WpL[j - 1] + bpL[j - 1]);

    const int b = p >> 9, l = p & 511;
    float4* qm4 = (float4*)(qmat + (size_t)p * 32);
    float*  kT  = kmatT + (size_t)b * 32 * 512 + l;

    for (int dq = 0; dq < 8; ++dq) {
        float q0 = bqL[4*dq+0], q1 = bqL[4*dq+1], q2 = bqL[4*dq+2], q3 = bqL[4*dq+3];
        float k0 = bkL[4*dq+0], k1 = bkL[4*dq+1], k2 = bkL[4*dq+2], k3 = bkL[4*dq+3];
        const float* wq = &WqL[(4*dq) * 32];
        const float* wk = &WkL[(4*dq) * 32];
        #pragma unroll
        for (int j = 0; j < 32; ++j) {
            const float ej = e[j];
            q0 = fmaf(wq[j],      ej, q0);
            q1 = fmaf(wq[32 + j], ej, q1);
            q2 = fmaf(wq[64 + j], ej, q2);
            q3 = fmaf(wq[96 + j], ej, q3);
            k0 = fmaf(wk[j],      ej, k0);
            k1 = fmaf(wk[32 + j], ej, k1);
            k2 = fmaf(wk[64 + j], ej, k2);
            k3 = fmaf(wk[96 + j], ej, k3);
        }
        qm4[dq] = make_float4(q0, q1, q2, q3);
        kT[(4*dq + 0) * 512] = k0;
        kT[(4*dq + 1) * 512] = k1;
        kT[(4*dq + 2) * 512] = k2;
        kT[(4*dq + 3) * 512] = k3;
    }
}

// ---------------------------------------------------------------------------
// Kernel 2: per-(b,q) attention -> att_out.  grid (32 qb, 8 b), 256 thr.
// ---------------------------------------------------------------------------
__global__ __launch_bounds__(256) void k_attn(
    const float* __restrict__ qmat, const float* __restrict__ kmatT,
    const float* __restrict__ val,  const int*   __restrict__ mark,
    const float* __restrict__ npm,  const float* __restrict__ Wo,
    const float* __restrict__ bo,   float* __restrict__ att)
{
    __shared__ float srow[4 * 512];   // per-wave score row
    __shared__ int   cc[512];         // category (-1 if padded)
    __shared__ float vv[512];         // values
    const int tid = threadIdx.x;
    const int qb  = blockIdx.x;       // 0..31
    const int b   = blockIdx.y;       // 0..7

    for (int k = tid; k < 512; k += 256) {
        const int   m  = mark[b * 512 + k];
        const float np = npm[b * 512 + k];
        cc[k] = (np > 0.0f) ? (m - 1) : -1;
        vv[k] = val[b * 512 + k];
    }
    __syncthreads();

    const int w = tid >> 6, lane = tid & 63;
    const float* kTb = kmatT + (size_t)b * 32 * 512;

    for (int iq = 0; iq < 4; ++iq) {
        const int q = qb * 16 + w * 4 + iq;

        float qr[32];
        const float4* qm4 = (const float4*)(qmat + (size_t)(b * 512 + q) * 32);
        #pragma unroll
        for (int j4 = 0; j4 < 8; ++j4) {
            float4 v = qm4[j4];
            qr[4*j4+0] = v.x; qr[4*j4+1] = v.y; qr[4*j4+2] = v.z; qr[4*j4+3] = v.w;
        }

        float acc[8];
        #pragma unroll
        for (int m = 0; m < 8; ++m) acc[m] = 0.0f;
        #pragma unroll 4
        for (int j = 0; j < 32; ++j) {
            const float* row = kTb + j * 512 + lane;
            const float  qj  = qr[j];
            #pragma unroll
            for (int m = 0; m < 8; ++m) acc[m] = fmaf(qj, row[m * 64], acc[m]);
        }
        #pragma unroll
        for (int m = 0; m < 8; ++m)
            srow[w * 512 + m * 64 + lane] = acc[m] * 0.17677669529663687f;
        __syncthreads();

        const int c = lane & 15, s = lane >> 4;
        float mx = -1e30f, Z = 0.0f, X = 0.0f;
        const int base = s * 128;
        for (int t = 0; t < 128; ++t) {
            const int k = base + ((t + s) & 127);
            if (cc[k] == c) {
                const float l  = (k <= q + WOFF_) ? srow[w * 512 + k] : 0.0f;
                const float mn = fmaxf(mx, l);
                const float e1 = __expf(l - mn);
                const float sc = __expf(mx - mn);
                Z = Z * sc + e1;
                X = X * sc + e1 * vv[k];
                mx = mn;
            }
        }
        #pragma unroll
        for (int off = 16; off <= 32; off <<= 1) {
            const float mo = __shfl_xor(mx, off);
            const float Zo = __shfl_xor(Z, off);
            const float Xo = __shfl_xor(X, off);
            const float mn = fmaxf(mx, mo);
            const float a0 = __expf(mx - mn);
            const float a1 = __expf(mo - mn);
            Z = Z * a0 + Zo * a1;
            X = X * a0 + Xo * a1;
            mx = mn;
        }
        const float x = (Z > 0.0f) ? X / Z : 0.0f;

        float xs[16];
        #pragma unroll
        for (int c2 = 0; c2 < 16; ++c2) xs[c2] = __shfl(x, c2);

        const float4* wo4 = (const float4*)(Wo + lane * 16);
        float a = bo[lane];
        #pragma unroll
        for (int c4 = 0; c4 < 4; ++c4) {
            float4 v = wo4[c4];
            a += xs[4*c4+0] * v.x + xs[4*c4+1] * v.y + xs[4*c4+2] * v.z + xs[4*c4+3] * v.w;
        }
        att[(size_t)(b * 512 + q) * 64 + lane] = a;
        __syncthreads();
    }
}

// ---------------------------------------------------------------------------
// Kernel 3: gi = att @ W_ih^T + b_ih.  256 blocks x 16 rows each.
// ---------------------------------------------------------------------------
__global__ __launch_bounds__(256) void k_gi(
    const float* __restrict__ att, const float* __restrict__ Wih,
    const float* __restrict__ bih, float* __restrict__ gi)
{
    __shared__ float WL[192 * 65];
    __shared__ float attL[16 * 64];
    __shared__ float bL[192];
    const int tid = threadIdx.x;

    for (int idx = tid; idx < 3072; idx += 256) {
        float4 v = ((const float4*)Wih)[idx];
        const int g = idx >> 4, jq = idx & 15;
        float* dst = &WL[g * 65 + jq * 4];
        dst[0] = v.x; dst[1] = v.y; dst[2] = v.z; dst[3] = v.w;
    }
    if (tid < 192) bL[tid] = bih[tid];
    {
        float4 v = ((const float4*)att)[blockIdx.x * 256 + tid];
        ((float4*)attL)[tid] = v;
    }
    __syncthreads();

    const size_t out0 = (size_t)blockIdx.x * 16 * 192;
    for (int pp = 0; pp < 12; ++pp) {
        const int p = tid + 256 * pp;
        const int r = p / 192, g = p - r * 192;
        float a0 = bL[g], a1 = 0.f, a2 = 0.f, a3 = 0.f;
        const float* wrow = &WL[g * 65];
        const float* arow = &attL[r * 64];
        #pragma unroll
        for (int j = 0; j < 64; j += 4) {
            a0 = fmaf(arow[j + 0], wrow[j + 0], a0);
            a1 = fmaf(arow[j + 1], wrow[j + 1], a1);
            a2 = fmaf(arow[j + 2], wrow[j + 2], a2);
            a3 = fmaf(arow[j + 3], wrow[j + 3], a3);
        }
        gi[out0 + p] = (a0 + a1) + (a2 + a3);
    }
}

// ---------------------------------------------------------------------------
// Kernel 4: sequential GRU — one wave per batch, LDS h-broadcast, no
// barrier, register-pressure-fitted issue stream.
//
// r5 post-mortem: 877 cy/step = 537 VALU + 340 stall. Lean VALU should be
// ~310 cy => ~230 cy/step register-plumbing tax. Cause: true arch-VGPR
// demand (192 weights + 64 upfront hp broadcast + ring + misc ~ 280) is
// over the 256 arch ceiling; the allocator spills state to AGPRs (gfx950
// unified file) and every AGPR-held operand costs a v_accvgpr_read copy
// before its v_pk_fma (~96-115 copies/step ~ 230 cy). Reported VGPR_Count
// 108-228 across rounds (all < 192 weight floats) corroborates.
//
// Fix: fit under 256 arch VGPRs.
//   - LDS broadcast reads software-pipelined 6 v4f-chunks ahead of
//     consumption (~28 hp regs live instead of 64; ~72 cy cover/chunk)
//   - gi ring 4-deep -> 2-deep (6 regs; 2 steps ~ 1100+ cy > 900 cy HBM)
//   => demand ~ 192 + 28 + 6 + 6 + ~18 = 250 < 256.
// FP op sequence bit-identical to rounds 0-5 (same pair-sequential
// accumulation order, same tail).
// ---------------------------------------------------------------------------

#define GRU_STEP(u, DO_REFILL) {                                           \
    v4f hv[16];                                                            \
    /* prologue: issue 6 chunks ahead */                                   \
    _Pragma("unroll")                                                      \
    for (int k = 0; k < 6; ++k) hv[k] = hs4[k];                            \
    const float gr = pr[u], gz = pz[u], gn = pn[u];                        \
    if (DO_REFILL) {                                                       \
        pr[u] = pf[0];                                                     \
        pz[u] = pf[64];                                                    \
        pn[u] = pf[128];                                                   \
        pf += 192;                                                         \
    }                                                                      \
    v2f ar2 = {gr + br, 0.0f};                                             \
    v2f az2 = {gz + bz, 0.0f};                                             \
    v2f an2 = {bn, 0.0f};                                                  \
    _Pragma("unroll")                                                      \
    for (int k = 0; k < 16; ++k) {                                         \
        if (k < 10) hv[k + 6] = hs4[k + 6];   /* stay 6 ahead */           \
        v2f p0 = __builtin_shufflevector(hv[k], hv[k], 0, 1);              \
        v2f p1 = __builtin_shufflevector(hv[k], hv[k], 2, 3);              \
        ar2 = wr[2*k]     * p0 + ar2;   /* v_pk_fma_f32 */                 \
        az2 = wz[2*k]     * p0 + az2;                                      \
        an2 = wn[2*k]     * p0 + an2;                                      \
        ar2 = wr[2*k + 1] * p1 + ar2;                                      \
        az2 = wz[2*k + 1] * p1 + az2;                                      \
        an2 = wn[2*k + 1] * p1 + an2;                                      \
    }                                                                      \
    const float ar = ar2.x + ar2.y;                                        \
    const float az = az2.x + az2.y;                                        \
    const float hn = an2.x + an2.y;                                        \
    const float r = __builtin_amdgcn_rcpf(1.0f + __expf(-ar));             \
    const float z = __builtin_amdgcn_rcpf(1.0f + __expf(-az));             \
    float npre = gn + r * hn;                                              \
    npre = fminf(fmaxf(npre, -15.0f), 15.0f);                              \
    const float e2 = __expf(2.0f * npre);                                  \
    const float n  = (e2 - 1.0f) * __builtin_amdgcn_rcpf(e2 + 1.0f);       \
    h = fmaf(z, h - n, n);            /* (1-z)*n + z*h */                  \
    hs[lane] = h;                     /* next step's broadcast source */   \
    *outp = h;                        /* fire-and-forget */                \
    outp += 64;                                                            \
}

__global__ __launch_bounds__(64, 1) void k_gru(
    const float* __restrict__ gi, const float* __restrict__ Whh,
    const float* __restrict__ bhh, float* __restrict__ out)
{
    __shared__ float hs[64];
    const int lane = threadIdx.x;     // 0..63
    const int b    = blockIdx.x;      // 0..7

    // Stage this lane's three W_hh rows into registers (as 32 x v2f each).
    v2f wr[32], wz[32], wn[32];
    {
        const v2f* r2 = (const v2f*)(Whh + (size_t)lane * 64);
        const v2f* z2 = (const v2f*)(Whh + (size_t)(lane + 64) * 64);
        const v2f* n2 = (const v2f*)(Whh + (size_t)(lane + 128) * 64);
        #pragma unroll
        for (int j = 0; j < 32; ++j) {
            wr[j] = r2[j];
            wz[j] = z2[j];
            wn[j] = n2[j];
        }
    }
    const float br = bhh[lane];
    const float bz = bhh[lane + 64];
    const float bn = bhh[lane + 128];

    const float* gib  = gi  + (size_t)b * 512 * 192;
    float*       outp = out + (size_t)b * 512 * 64 + lane;

    float h = 0.0f;
    hs[lane] = 0.0f;                  // h_{-1} = 0 (same wave; DS in-order)

    // 2-deep gi prefetch ring
    float pr[2], pz[2], pn[2];
    #pragma unroll
    for (int i = 0; i < 2; ++i) {
        const float* gp = gib + (size_t)i * 192;
        pr[i] = gp[lane];
        pz[i] = gp[lane + 64];
        pn[i] = gp[lane + 128];
    }
    // refill pointer: lane offset baked in, advanced +192 per step
    const float* pf = gib + (size_t)2 * 192 + lane;

    const v4f* hs4 = (const v4f*)hs;

    // main loop: 255 groups of 2, steps 0..509, refills rows 2..511
    for (int tt = 0; tt < 510; tt += 2) {
        GRU_STEP(0, 1)
        GRU_STEP(1, 1)
    }
    // epilogue: steps 510..511 from the ring, no refill
    GRU_STEP(0, 0)
    GRU_STEP(1, 0)
}

// ---------------------------------------------------------------------------
extern "C" void kernel_launch(void* const* d_in, const int* in_sizes, int n_in,
                              void* d_out, int out_size, void* d_ws, size_t ws_size,
                              hipStream_t stream)
{
    const float* ts   = (const float*)d_in[0];
    const float* val  = (const float*)d_in[1];
    const int*   mark = (const int*)  d_in[2];
    const float* npm  = (const float*)d_in[3];
    const float* Wl   = (const float*)d_in[4];
    const float* bl   = (const float*)d_in[5];
    const float* Wp   = (const float*)d_in[6];
    const float* bp   = (const float*)d_in[7];
    const float* Wq   = (const float*)d_in[8];
    const float* bq   = (const float*)d_in[9];
    const float* Wk   = (const float*)d_in[10];
    const float* bk   = (const float*)d_in[11];
    const float* Wo   = (const float*)d_in[12];
    const float* bo   = (const float*)d_in[13];
    const float* Wih  = (const float*)d_in[14];
    const float* Whh  = (const float*)d_in[15];
    const float* bih  = (const float*)d_in[16];
    const float* bhh  = (const float*)d_in[17];

    float* ws    = (float*)d_ws;
    float* qmat  = ws;                 // 131072
    float* kmatT = ws + 131072;        // 131072
    float* att   = ws + 262144;        // 262144
    float* gi    = ws + 524288;        // 786432
    float* out   = (float*)d_out;

    k_embed<<<16, 256, 0, stream>>>(ts, Wl, bl, Wp, bp, Wq, bq, Wk, bk, qmat, kmatT);
    k_attn<<<dim3(32, 8), 256, 0, stream>>>(qmat, kmatT, val, mark, npm, Wo, bo, att);
    k_gi<<<256, 256, 0, stream>>>(att, Wih, bih, gi);
    k_gru<<<8, 64, 0, stream>>>(gi, Whh, bhh, out);
}